// Round 7
// baseline (361.290 us; speedup 1.0000x reference)
//
#include <hip/hip_runtime.h>
#include <hip/hip_bf16.h>
#include <cstdint>
#include <cstddef>

#define TOK    8192
#define DMODEL 1024
#define HDIM   2048
#define MDIM   64
#define NEXP   8
#define HHALF  1024

using f32x4  = __attribute__((ext_vector_type(4))) float;
using bf16x8 = __attribute__((ext_vector_type(8))) __bf16;
using bf16x4 = __attribute__((ext_vector_type(4))) __bf16;

// async global->LDS, 16B per lane. LDS dest is wave-uniform base + lane*16.
__device__ __forceinline__ void async16(const void* g, void* l) {
  __builtin_amdgcn_global_load_lds(
      (const __attribute__((address_space(1))) unsigned int*)g,
      (__attribute__((address_space(3))) unsigned int*)l, 16, 0, 0);
}

__global__ __launch_bounds__(256) void cvt_bf16_kernel(
    const float* __restrict__ in, __bf16* __restrict__ out, int n4) {
  int i = blockIdx.x * 256 + threadIdx.x;
  if (i >= n4) return;
  float4 v = ((const float4*)in)[i];
  bf16x4 o = { (__bf16)v.x, (__bf16)v.y, (__bf16)v.z, (__bf16)v.w };
  ((bf16x4*)out)[i] = o;
}

__global__ __launch_bounds__(256) void transpose_cvt_kernel(
    const float* __restrict__ in, __bf16* __restrict__ out, int R, int C) {
  __shared__ float t[32][33];
  size_t bo = (size_t)blockIdx.z * R * C;
  const float* inp = in + bo;
  __bf16* outp = out + bo;
  int c0 = blockIdx.x * 32, r0 = blockIdx.y * 32;
  int x = threadIdx.x & 31, y = threadIdx.x >> 5;
  #pragma unroll
  for (int i = y; i < 32; i += 8) t[i][x] = inp[(size_t)(r0 + i) * C + c0 + x];
  __syncthreads();
  #pragma unroll
  for (int i = y; i < 32; i += 8)
    outp[(size_t)(c0 + i) * R + r0 + x] = (__bf16)t[x][i];
}

// C = act(A @ Bt^T [+ bias]); A: MxK bf16 (row-major), Bt: NxK bf16.
// BK=64, global_load_lds staging with HOISTED pointers (+BK/iter),
// XOR-swizzled 16B chunks, precomputed loop-invariant LDS read offsets.
// Split-K via gridDim.z: z-slice computes K/gridDim.z, writes slab at Cout + z*M*N.
template <int BM, int BN, int OUT_BF16, int ACT, int BIAS>
__global__ __launch_bounds__(256) void gemm_bt(
    const __bf16* __restrict__ A, const __bf16* __restrict__ Bt,
    const float* __restrict__ bias, void* __restrict__ Cout,
    int M, int N, int K) {
  constexpr int BK = 64;               // 8 chunks of 16B per row
  constexpr int WTM = BM / 32;
  constexpr int WTN = BN / 32;
  __shared__ __bf16 As[BM * BK];
  __shared__ __bf16 Bs[BN * BK];
  const int tid = threadIdx.x;
  const int wave = tid >> 6, lane = tid & 63;
  const int quad = lane >> 4, l16 = lane & 15;
  const int m0 = blockIdx.x * BM, n0 = blockIdx.y * BN;
  const int ks = K / gridDim.z;
  const int kbeg = blockIdx.z * ks;
  const int wm = (wave & 1) * (BM / 2);
  const int wn = (wave >> 1) * (BN / 2);
  const int lrow = lane >> 3;          // row within 8-row group
  const int lchunk = lane & 7;         // physical 16B chunk (LDS slot fixed by lane)
  constexpr int A_ISSUES = BM / 32;
  constexpr int B_ISSUES = BN / 32;
  f32x4 acc[WTM][WTN] = {};

  // hoisted global source pointers (swizzled); bumped by +BK per iteration
  const __bf16* aSrc[A_ISSUES];
  const __bf16* bSrc[B_ISSUES];
  #pragma unroll
  for (int t = 0; t < A_ISSUES; ++t) {
    int row = (t * 4 + wave) * 8 + lrow;
    aSrc[t] = A + (size_t)(m0 + row) * K + kbeg + (lchunk ^ (row & 7)) * 8;
  }
  #pragma unroll
  for (int t = 0; t < B_ISSUES; ++t) {
    int row = (t * 4 + wave) * 8 + lrow;
    bSrc[t] = Bt + (size_t)(n0 + row) * K + kbeg + (lchunk ^ (row & 7)) * 8;
  }
  // loop-invariant LDS read offsets (element units)
  int aOff[WTM][2], bOff[WTN][2];
  #pragma unroll
  for (int i = 0; i < WTM; ++i) {
    int row = wm + i * 16 + l16;
    #pragma unroll
    for (int kk = 0; kk < 2; ++kk)
      aOff[i][kk] = row * BK + (((kk * 4 + quad) ^ (row & 7)) * 8);
  }
  #pragma unroll
  for (int j = 0; j < WTN; ++j) {
    int row = wn + j * 16 + l16;
    #pragma unroll
    for (int kk = 0; kk < 2; ++kk)
      bOff[j][kk] = row * BK + (((kk * 4 + quad) ^ (row & 7)) * 8);
  }

  const int niter = ks / BK;
  for (int it = 0; it < niter; ++it) {
    __syncthreads();
    #pragma unroll
    for (int t = 0; t < A_ISSUES; ++t) {
      async16(aSrc[t], As + (t * 4 + wave) * 8 * BK);
      aSrc[t] += BK;
    }
    #pragma unroll
    for (int t = 0; t < B_ISSUES; ++t) {
      async16(bSrc[t], Bs + (t * 4 + wave) * 8 * BK);
      bSrc[t] += BK;
    }
    __syncthreads();
    #pragma unroll
    for (int kk = 0; kk < 2; ++kk) {
      bf16x8 af[WTM], bfr[WTN];
      #pragma unroll
      for (int i = 0; i < WTM; ++i) af[i] = *(const bf16x8*)(As + aOff[i][kk]);
      #pragma unroll
      for (int j = 0; j < WTN; ++j) bfr[j] = *(const bf16x8*)(Bs + bOff[j][kk]);
      #pragma unroll
      for (int i = 0; i < WTM; ++i)
        #pragma unroll
        for (int j = 0; j < WTN; ++j)
          acc[i][j] = __builtin_amdgcn_mfma_f32_16x16x32_bf16(af[i], bfr[j], acc[i][j], 0, 0, 0);
    }
  }

  char* Cz = (char*)Cout + (size_t)blockIdx.z * M * N * (OUT_BF16 ? 2 : 4);
  #pragma unroll
  for (int i = 0; i < WTM; ++i)
    #pragma unroll
    for (int j = 0; j < WTN; ++j)
      #pragma unroll
      for (int r = 0; r < 4; ++r) {
        int m = m0 + wm + i * 16 + quad * 4 + r;
        int n = n0 + wn + j * 16 + l16;
        float v = acc[i][j][r];
        if (BIAS) v += bias[n];
        if (ACT == 1) v = 1.0f / (1.0f + __expf(-v));
        if (OUT_BF16)
          ((__bf16*)Cz)[(size_t)m * N + n] = (__bf16)v;
        else
          ((float*)Cz)[(size_t)m * N + n] = v;
      }
}

// Router: split-K reduce + 2-layer router + top-2 -> per-token packed pair
// + normalized gates. No atomics. One wave per token.
__global__ __launch_bounds__(256) void router_kernel(
    const float* __restrict__ contP, const float* __restrict__ s2c_b,
    const float* __restrict__ rW1, const float* __restrict__ rb1,
    const float* __restrict__ rW2, const float* __restrict__ rb2,
    __bf16* __restrict__ contB, int* __restrict__ e01,
    float2* __restrict__ g01) {
  const int wave = threadIdx.x >> 6, lane = threadIdx.x & 63;
  const int n = blockIdx.x * 4 + wave;
  const size_t base = (size_t)n * 64 + lane;
  const size_t slab = (size_t)TOK * 64;
  float c = contP[base] + contP[base + slab] + contP[base + 2 * slab] +
            contP[base + 3 * slab] + s2c_b[lane];
  contB[base] = (__bf16)c;
  float acc = rb1[lane];
  #pragma unroll
  for (int i = 0; i < 64; ++i) {
    float ci = __shfl(c, i);
    acc = fmaf(ci, rW1[i * 64 + lane], acc);
  }
  float t = tanhf(acc);
  float logit[8];
  #pragma unroll
  for (int e = 0; e < 8; ++e) {
    float v = t * rW2[lane * 8 + e];
    #pragma unroll
    for (int o = 32; o; o >>= 1) v += __shfl_xor(v, o);
    logit[e] = v + rb2[e];
  }
  float mx = logit[0];
  #pragma unroll
  for (int e = 1; e < 8; ++e) mx = fmaxf(mx, logit[e]);
  float p[8];
  #pragma unroll
  for (int e = 0; e < 8; ++e) p[e] = __expf(logit[e] - mx);
  float v0 = p[0]; int e0 = 0;
  #pragma unroll
  for (int e = 1; e < 8; ++e) if (p[e] > v0) { v0 = p[e]; e0 = e; }
  float v1 = -1.0f; int e1 = 0;
  #pragma unroll
  for (int e = 0; e < 8; ++e) if (e != e0 && p[e] > v1) { v1 = p[e]; e1 = e; }
  float inv = 1.0f / (v0 + v1);
  if (lane == 0) {
    e01[n] = e0 | (e1 << 8);
    g01[n] = make_float2(v0 * inv, v1 * inv);
  }
}

// Deterministic compaction: one block per expert, ballot+popcount wave rank,
// LDS prefix across the 4 waves, zero contended global atomics.
__global__ __launch_bounds__(256) void compact_kernel(
    const int* __restrict__ e01, const float2* __restrict__ g01,
    int* __restrict__ cnt, int* __restrict__ tlist, float* __restrict__ glist) {
  const int e = blockIdx.x;
  const int tid = threadIdx.x;
  const int wave = tid >> 6, lane = tid & 63;
  __shared__ int wcnt[4];
  __shared__ int running;
  if (tid == 0) running = 0;
  __syncthreads();
  for (int base = 0; base < TOK; base += 256) {
    const int t = base + tid;
    const int p = e01[t];
    const float2 g = g01[t];
    const bool m0 = (p & 0xff) == e;
    const bool m1 = ((p >> 8) & 0xff) == e;
    const bool m = m0 || m1;
    const float gv = m0 ? g.x : g.y;
    unsigned long long mask = __ballot(m);
    int rank = __popcll(mask & ((1ull << lane) - 1ull));
    if (lane == 0) wcnt[wave] = __popcll(mask);
    __syncthreads();
    int off = running;
    for (int w = 0; w < wave; ++w) off += wcnt[w];
    if (m) {
      int pos = off + rank;
      tlist[e * TOK + pos] = t;
      glist[e * TOK + pos] = gv;
    }
    __syncthreads();
    if (tid == 0) running += wcnt[0] + wcnt[1] + wcnt[2] + wcnt[3];
    __syncthreads();
  }
  if (tid == 0) cnt[e] = running;
}

// Gathered MoE: block = 128 compacted tokens of expert e; swizzled LDS tiles.
__global__ __launch_bounds__(256) void moe_fused_kernel(
    const __bf16* __restrict__ contB, const __bf16* __restrict__ We1T,
    const __bf16* __restrict__ We2T, const float* __restrict__ be1,
    const float* __restrict__ be2, const int* __restrict__ cnt,
    const int* __restrict__ tlist, const float* __restrict__ glist,
    float* __restrict__ out_flat) {
  constexpr int TT = 128;
  const int e = blockIdx.y;
  const int slot0 = blockIdx.x * TT;
  const int count = cnt[e];
  if (slot0 >= count) return;
  __shared__ __bf16 cont_s[TT * 64];
  __shared__ __bf16 w1_s[64 * 64];
  __shared__ __bf16 w2_s[64 * 64];
  __shared__ __bf16 h_s[TT * 64];
  __shared__ int tok_s[TT];
  __shared__ float g_s[TT];
  const int tid = threadIdx.x;
  const int wave = tid >> 6, lane = tid & 63;
  const int quad = lane >> 4, l16 = lane & 15;
  if (tid < TT) {
    int slot = slot0 + tid;
    bool valid = slot < count;
    tok_s[tid] = valid ? tlist[e * TOK + slot] : 0;
    g_s[tid]  = valid ? glist[e * TOK + slot] : 0.0f;
  }
  __syncthreads();
  for (int i = tid; i < TT * 8; i += 256) {   // gather cont rows (8x16B each)
    int r = i >> 3, cc = i & 7;
    *(uint4*)(cont_s + r * 64 + ((cc ^ (r & 7)) * 8)) =
        *(const uint4*)(contB + (size_t)tok_s[r] * 64 + cc * 8);
  }
  const int wtok = wave * 32;
  f32x4 acc2[2][4] = {};
  for (int hc = 0; hc < HHALF; hc += 64) {
    __syncthreads();
    for (int c = tid; c < 512; c += 256) {
      int r = c >> 3, cc = c & 7;
      *(uint4*)(w1_s + r * 64 + ((cc ^ (r & 7)) * 8)) =
          *(const uint4*)(We1T + ((size_t)e * HHALF + hc + r) * 64 + cc * 8);
      *(uint4*)(w2_s + r * 64 + ((cc ^ (r & 7)) * 8)) =
          *(const uint4*)(We2T + ((size_t)e * 64 + r) * HHALF + hc + cc * 8);
    }
    __syncthreads();
    f32x4 acc1[2][4] = {};
    #pragma unroll
    for (int kk = 0; kk < 2; ++kk) {
      bf16x8 af[2], bfr[4];
      #pragma unroll
      for (int i = 0; i < 2; ++i) {
        int row = wtok + i * 16 + l16;
        af[i] = *(const bf16x8*)(cont_s + row * 64 + (((kk * 4 + quad) ^ (row & 7)) * 8));
      }
      #pragma unroll
      for (int j = 0; j < 4; ++j) {
        int row = j * 16 + l16;
        bfr[j] = *(const bf16x8*)(w1_s + row * 64 + (((kk * 4 + quad) ^ (row & 7)) * 8));
      }
      #pragma unroll
      for (int i = 0; i < 2; ++i)
        #pragma unroll
        for (int j = 0; j < 4; ++j)
          acc1[i][j] = __builtin_amdgcn_mfma_f32_16x16x32_bf16(af[i], bfr[j], acc1[i][j], 0, 0, 0);
    }
    #pragma unroll
    for (int i = 0; i < 2; ++i)
      #pragma unroll
      for (int j = 0; j < 4; ++j)
        #pragma unroll
        for (int r = 0; r < 4; ++r) {
          int tr = wtok + i * 16 + quad * 4 + r;
          int hcol = j * 16 + l16;
          float v = acc1[i][j][r] + be1[e * HHALF + hc + hcol];
          h_s[tr * 64 + (((hcol >> 3) ^ (tr & 7)) * 8) + (hcol & 7)] =
              (__bf16)fmaxf(v, 0.0f);
        }
    #pragma unroll
    for (int kk = 0; kk < 2; ++kk) {
      bf16x8 af[2], bfr[4];
      #pragma unroll
      for (int i = 0; i < 2; ++i) {
        int row = wtok + i * 16 + l16;
        af[i] = *(const bf16x8*)(h_s + row * 64 + (((kk * 4 + quad) ^ (row & 7)) * 8));
      }
      #pragma unroll
      for (int j = 0; j < 4; ++j) {
        int row = j * 16 + l16;
        bfr[j] = *(const bf16x8*)(w2_s + row * 64 + (((kk * 4 + quad) ^ (row & 7)) * 8));
      }
      #pragma unroll
      for (int i = 0; i < 2; ++i)
        #pragma unroll
        for (int j = 0; j < 4; ++j)
          acc2[i][j] = __builtin_amdgcn_mfma_f32_16x16x32_bf16(af[i], bfr[j], acc2[i][j], 0, 0, 0);
    }
  }
  #pragma unroll
  for (int i = 0; i < 2; ++i)
    #pragma unroll
    for (int j = 0; j < 4; ++j)
      #pragma unroll
      for (int r = 0; r < 4; ++r) {
        int tr = wtok + i * 16 + quad * 4 + r;
        int m = j * 16 + l16;
        float g = g_s[tr];
        if (g != 0.0f)
          atomicAdd(out_flat + (size_t)tok_s[tr] * 64 + m,
                    g * (acc2[i][j][r] + be2[e * 64 + m]));
      }
}

__global__ __launch_bounds__(256) void ln_kernel(
    const float* __restrict__ x, const float* __restrict__ g,
    const float* __restrict__ b, float* __restrict__ out) {
  const int row = blockIdx.x;
  const float4 v = ((const float4*)(x + (size_t)row * 1024))[threadIdx.x];
  float s1 = v.x + v.y + v.z + v.w;
  float s2 = v.x * v.x + v.y * v.y + v.z * v.z + v.w * v.w;
  #pragma unroll
  for (int o = 32; o; o >>= 1) { s1 += __shfl_xor(s1, o); s2 += __shfl_xor(s2, o); }
  __shared__ float ws1[4], ws2[4];
  const int wave = threadIdx.x >> 6, lane = threadIdx.x & 63;
  if (lane == 0) { ws1[wave] = s1; ws2[wave] = s2; }
  __syncthreads();
  s1 = ws1[0] + ws1[1] + ws1[2] + ws1[3];
  s2 = ws2[0] + ws2[1] + ws2[2] + ws2[3];
  const float mu = s1 * (1.0f / 1024.0f);
  const float var = s2 * (1.0f / 1024.0f) - mu * mu;
  const float inv = rsqrtf(var + 1e-5f);
  const int col = threadIdx.x * 4;
  const float4 gv = *(const float4*)(g + col);
  const float4 bv = *(const float4*)(b + col);
  float4 o;
  o.x = (v.x - mu) * inv * gv.x + bv.x;
  o.y = (v.y - mu) * inv * gv.y + bv.y;
  o.z = (v.z - mu) * inv * gv.z + bv.z;
  o.w = (v.w - mu) * inv * gv.w + bv.w;
  *(float4*)(out + (size_t)row * 1024 + col) = o;
}

extern "C" void kernel_launch(void* const* d_in, const int* in_sizes, int n_in,
                              void* d_out, int out_size, void* d_ws, size_t ws_size,
                              hipStream_t stream) {
  const float* X     = (const float*)d_in[0];
  const float* enc_W = (const float*)d_in[1];
  const float* enc_b = (const float*)d_in[2];
  const float* s2c_W = (const float*)d_in[3];
  const float* s2c_b = (const float*)d_in[4];
  const float* rW1   = (const float*)d_in[5];
  const float* rb1   = (const float*)d_in[6];
  const float* rW2   = (const float*)d_in[7];
  const float* rb2   = (const float*)d_in[8];
  const float* We1   = (const float*)d_in[9];
  const float* be1   = (const float*)d_in[10];
  const float* We2   = (const float*)d_in[11];
  const float* be2   = (const float*)d_in[12];
  const float* c2s_W = (const float*)d_in[13];
  const float* c2s_b = (const float*)d_in[14];
  const float* dec_W = (const float*)d_in[15];
  const float* dec_b = (const float*)d_in[16];
  const float* ln_g  = (const float*)d_in[17];
  const float* ln_b  = (const float*)d_in[18];
  float* out = (float*)d_out;

  // ---- workspace layout with explicit aliasing (~78.5 MB total) ----
  char* ws = (char*)d_ws;
  size_t off = 0;
  auto take = [&](size_t bytes) -> char* {
    char* p = ws + off;
    off = (off + bytes + 255) & ~(size_t)255;
    return p;
  };
  const size_t SLAB = (size_t)TOK * HDIM * 2;       // 33,554,432
  char*   slabA     = take(SLAB);
  char*   slabB     = take(SLAB);
  __bf16* encWT     = (__bf16*)take((size_t)HDIM * DMODEL * 2);
  __bf16* s2cWT     = (__bf16*)take((size_t)MDIM * HDIM * 2);
  __bf16* c2sWT     = (__bf16*)take((size_t)HDIM * MDIM * 2);
  __bf16* decWT     = (__bf16*)take((size_t)DMODEL * HDIM * 2);
  __bf16* We1T      = (__bf16*)take((size_t)NEXP * HHALF * MDIM * 2);
  __bf16* We2T      = (__bf16*)take((size_t)NEXP * MDIM * HHALF * 2);
  __bf16* contB     = (__bf16*)take((size_t)TOK * MDIM * 2);
  int*    cnt       = (int*)take(256);
  int*    e01       = (int*)take((size_t)TOK * 4);
  float2* g01       = (float2*)take((size_t)TOK * 8);
  int*    tlist     = (int*)take((size_t)NEXP * TOK * 4);
  float*  glist     = (float*)take((size_t)NEXP * TOK * 4);
  float*  outFlat   = (float*)take((size_t)TOK * MDIM * 4);
  __bf16* outFlatB  = (__bf16*)take((size_t)TOK * MDIM * 2);
  if (off > ws_size) return;  // insufficient workspace -> clean correctness fail

  __bf16* Xb        = (__bf16*)slabA;                       // dead after GEMM1
  float*  contP     = (float*)(slabA + (size_t)TOK * DMODEL * 2);  // dead after router
  __bf16* spikesMoe = (__bf16*)slabA;                       // born at GEMM3
  __bf16* spikesEnc = (__bf16*)slabB;                       // dead after GEMM2
  float*  decoded   = (float*)slabB;                        // born at GEMM4

  hipMemsetAsync(outFlat, 0, (size_t)TOK * MDIM * 4, stream);

  cvt_bf16_kernel<<<TOK * DMODEL / 4 / 256, 256, 0, stream>>>(X, Xb, TOK * DMODEL / 4);
  transpose_cvt_kernel<<<dim3(HDIM / 32, DMODEL / 32, 1), 256, 0, stream>>>(enc_W, encWT, DMODEL, HDIM);
  transpose_cvt_kernel<<<dim3(MDIM / 32, HDIM / 32, 1), 256, 0, stream>>>(s2c_W, s2cWT, HDIM, MDIM);
  transpose_cvt_kernel<<<dim3(HDIM / 32, MDIM / 32, 1), 256, 0, stream>>>(c2s_W, c2sWT, MDIM, HDIM);
  transpose_cvt_kernel<<<dim3(DMODEL / 32, HDIM / 32, 1), 256, 0, stream>>>(dec_W, decWT, HDIM, DMODEL);
  transpose_cvt_kernel<<<dim3(HHALF / 32, MDIM / 32, NEXP), 256, 0, stream>>>(We1, We1T, MDIM, HHALF);
  transpose_cvt_kernel<<<dim3(MDIM / 32, HHALF / 32, NEXP), 256, 0, stream>>>(We2, We2T, HHALF, MDIM);

  // GEMM1: spikesEnc = sigmoid(X @ enc_W + b)   8192x2048, K=1024
  gemm_bt<128, 128, 1, 1, 1><<<dim3(TOK / 128, HDIM / 128, 1), 256, 0, stream>>>(
      Xb, encWT, enc_b, spikesEnc, TOK, HDIM, DMODEL);
  // GEMM2 (split-K x4): contP[z] = spikesEnc @ s2c_W partials   8192x64, K=2048
  gemm_bt<128, 64, 0, 0, 0><<<dim3(TOK / 128, 1, 4), 256, 0, stream>>>(
      spikesEnc, s2cWT, nullptr, contP, TOK, MDIM, HDIM);
  // router: reduce partials + bias, top-2 -> e01/g01 (no atomics)
  router_kernel<<<TOK / 4, 256, 0, stream>>>(contP, s2c_b, rW1, rb1, rW2, rb2,
                                             contB, e01, g01);
  // deterministic per-expert compaction (ballot/prefix, no contended atomics)
  compact_kernel<<<NEXP, 256, 0, stream>>>(e01, g01, cnt, tlist, glist);
  // gathered MoE -> outFlat (fp32; exactly 2 atomic adds per element)
  moe_fused_kernel<<<dim3(TOK / 128, NEXP), 256, 0, stream>>>(
      contB, We1T, We2T, be1, be2, cnt, tlist, glist, outFlat);
  cvt_bf16_kernel<<<TOK * MDIM / 4 / 256, 256, 0, stream>>>(outFlat, outFlatB, TOK * MDIM / 4);
  // GEMM3: spikesMoe = sigmoid(outFlat @ c2s_W + b)   8192x2048, K=64
  gemm_bt<128, 128, 1, 1, 1><<<dim3(TOK / 128, HDIM / 128, 1), 256, 0, stream>>>(
      outFlatB, c2sWT, c2s_b, spikesMoe, TOK, HDIM, MDIM);
  // GEMM4: decoded = sigmoid(spikesMoe @ dec_W + b)   8192x1024, K=2048
  gemm_bt<128, 128, 0, 1, 1><<<dim3(TOK / 128, DMODEL / 128, 1), 256, 0, stream>>>(
      spikesMoe, decWT, dec_b, decoded, TOK, DMODEL, HDIM);
  ln_kernel<<<TOK, 256, 0, stream>>>(decoded, ln_g, ln_b, out);
}

// Round 8
// 325.872 us; speedup vs baseline: 1.1087x; 1.1087x over previous
//
#include <hip/hip_runtime.h>
#include <hip/hip_bf16.h>
#include <cstdint>
#include <cstddef>

#define TOK    8192
#define DMODEL 1024
#define HDIM   2048
#define MDIM   64
#define NEXP   8
#define HHALF  1024

using f32x4  = __attribute__((ext_vector_type(4))) float;
using bf16x8 = __attribute__((ext_vector_type(8))) __bf16;
using bf16x4 = __attribute__((ext_vector_type(4))) __bf16;

// async global->LDS, 16B per lane. LDS dest is wave-uniform base + lane*16.
__device__ __forceinline__ void async16(const void* g, void* l) {
  __builtin_amdgcn_global_load_lds(
      (const __attribute__((address_space(1))) unsigned int*)g,
      (__attribute__((address_space(3))) unsigned int*)l, 16, 0, 0);
}

__global__ __launch_bounds__(256) void cvt_bf16_kernel(
    const float* __restrict__ in, __bf16* __restrict__ out, int n4) {
  int i = blockIdx.x * 256 + threadIdx.x;
  if (i >= n4) return;
  float4 v = ((const float4*)in)[i];
  bf16x4 o = { (__bf16)v.x, (__bf16)v.y, (__bf16)v.z, (__bf16)v.w };
  ((bf16x4*)out)[i] = o;
}

// One-launch preamble: cvt(X) + transpose-cvt of all 6 weight tensors.
// Job selected by linear block id; branches are block-uniform.
__global__ __launch_bounds__(256) void preamble_kernel(
    const float* __restrict__ X, __bf16* __restrict__ Xb,
    const float* __restrict__ encW, __bf16* __restrict__ encWT,
    const float* __restrict__ s2cW, __bf16* __restrict__ s2cWT,
    const float* __restrict__ c2sW, __bf16* __restrict__ c2sWT,
    const float* __restrict__ decW, __bf16* __restrict__ decWT,
    const float* __restrict__ We1, __bf16* __restrict__ We1T,
    const float* __restrict__ We2, __bf16* __restrict__ We2T) {
  __shared__ float ts[32][33];
  const int tid = threadIdx.x;
  int b = blockIdx.x;
  if (b < 8192) {  // X: 8192x1024 fp32 -> bf16 (float4 per thread)
    int i = b * 256 + tid;
    float4 v = ((const float4*)X)[i];
    bf16x4 o = { (__bf16)v.x, (__bf16)v.y, (__bf16)v.z, (__bf16)v.w };
    ((bf16x4*)Xb)[i] = o;
    return;
  }
  b -= 8192;
  const float* in; __bf16* outp; int R, C, tx, ty;
  if (b < 2048)              { in = encW; outp = encWT; R = 1024; C = 2048; tx = b % 64; ty = b / 64; }
  else if ((b -= 2048) < 128){ in = s2cW; outp = s2cWT; R = 2048; C = 64;   tx = b % 2;  ty = b / 2;  }
  else if ((b -= 128) < 128) { in = c2sW; outp = c2sWT; R = 64;   C = 2048; tx = b % 64; ty = b / 64; }
  else if ((b -= 128) < 2048){ in = decW; outp = decWT; R = 2048; C = 1024; tx = b % 32; ty = b / 32; }
  else if ((b -= 2048) < 512){ int s = b / 64, t = b % 64;
                               in = We1 + (size_t)s * 65536; outp = We1T + (size_t)s * 65536;
                               R = 64; C = 1024; tx = t % 32; ty = t / 32; }
  else                       { b -= 512; int s = b / 64, t = b % 64;
                               in = We2 + (size_t)s * 65536; outp = We2T + (size_t)s * 65536;
                               R = 1024; C = 64; tx = t % 2; ty = t / 2; }
  const int c0 = tx * 32, r0 = ty * 32;
  const int x = tid & 31, y = tid >> 5;
  #pragma unroll
  for (int i = y; i < 32; i += 8) ts[i][x] = in[(size_t)(r0 + i) * C + c0 + x];
  __syncthreads();
  #pragma unroll
  for (int i = y; i < 32; i += 8)
    outp[(size_t)(c0 + i) * R + r0 + x] = (__bf16)ts[x][i];
}
#define PREAMBLE_BLOCKS (8192 + 2048 + 128 + 128 + 2048 + 512 + 512)

// C = act(A @ Bt^T [+ bias]); A: MxK bf16 (row-major), Bt: NxK bf16.
// BK=64, global_load_lds staging, XOR-swizzled 16B chunks, hoisted pointers.
// Split-K via gridDim.z: z-slice computes K/gridDim.z, writes slab at Cout + z*M*N.
template <int BM, int BN, int OUT_BF16, int ACT, int BIAS>
__global__ __launch_bounds__(256) void gemm_bt(
    const __bf16* __restrict__ A, const __bf16* __restrict__ Bt,
    const float* __restrict__ bias, void* __restrict__ Cout,
    int M, int N, int K) {
  constexpr int BK = 64;               // 8 chunks of 16B per row
  constexpr int WTM = BM / 32;
  constexpr int WTN = BN / 32;
  __shared__ __bf16 As[BM * BK];
  __shared__ __bf16 Bs[BN * BK];
  const int tid = threadIdx.x;
  const int wave = tid >> 6, lane = tid & 63;
  const int quad = lane >> 4, l16 = lane & 15;
  const int m0 = blockIdx.x * BM, n0 = blockIdx.y * BN;
  const int ks = K / gridDim.z;
  const int kbeg = blockIdx.z * ks;
  const int wm = (wave & 1) * (BM / 2);
  const int wn = (wave >> 1) * (BN / 2);
  const int lrow = lane >> 3;
  const int lchunk = lane & 7;
  constexpr int A_ISSUES = BM / 32;
  constexpr int B_ISSUES = BN / 32;
  f32x4 acc[WTM][WTN] = {};

  const __bf16* aSrc[A_ISSUES];
  const __bf16* bSrc[B_ISSUES];
  #pragma unroll
  for (int t = 0; t < A_ISSUES; ++t) {
    int row = (t * 4 + wave) * 8 + lrow;
    aSrc[t] = A + (size_t)(m0 + row) * K + kbeg + (lchunk ^ (row & 7)) * 8;
  }
  #pragma unroll
  for (int t = 0; t < B_ISSUES; ++t) {
    int row = (t * 4 + wave) * 8 + lrow;
    bSrc[t] = Bt + (size_t)(n0 + row) * K + kbeg + (lchunk ^ (row & 7)) * 8;
  }
  int aOff[WTM][2], bOff[WTN][2];
  #pragma unroll
  for (int i = 0; i < WTM; ++i) {
    int row = wm + i * 16 + l16;
    #pragma unroll
    for (int kk = 0; kk < 2; ++kk)
      aOff[i][kk] = row * BK + (((kk * 4 + quad) ^ (row & 7)) * 8);
  }
  #pragma unroll
  for (int j = 0; j < WTN; ++j) {
    int row = wn + j * 16 + l16;
    #pragma unroll
    for (int kk = 0; kk < 2; ++kk)
      bOff[j][kk] = row * BK + (((kk * 4 + quad) ^ (row & 7)) * 8);
  }

  const int niter = ks / BK;
  for (int it = 0; it < niter; ++it) {
    __syncthreads();
    #pragma unroll
    for (int t = 0; t < A_ISSUES; ++t) {
      async16(aSrc[t], As + (t * 4 + wave) * 8 * BK);
      aSrc[t] += BK;
    }
    #pragma unroll
    for (int t = 0; t < B_ISSUES; ++t) {
      async16(bSrc[t], Bs + (t * 4 + wave) * 8 * BK);
      bSrc[t] += BK;
    }
    __syncthreads();
    #pragma unroll
    for (int kk = 0; kk < 2; ++kk) {
      bf16x8 af[WTM], bfr[WTN];
      #pragma unroll
      for (int i = 0; i < WTM; ++i) af[i] = *(const bf16x8*)(As + aOff[i][kk]);
      #pragma unroll
      for (int j = 0; j < WTN; ++j) bfr[j] = *(const bf16x8*)(Bs + bOff[j][kk]);
      #pragma unroll
      for (int i = 0; i < WTM; ++i)
        #pragma unroll
        for (int j = 0; j < WTN; ++j)
          acc[i][j] = __builtin_amdgcn_mfma_f32_16x16x32_bf16(af[i], bfr[j], acc[i][j], 0, 0, 0);
    }
  }

  char* Cz = (char*)Cout + (size_t)blockIdx.z * M * N * (OUT_BF16 ? 2 : 4);
  #pragma unroll
  for (int i = 0; i < WTM; ++i)
    #pragma unroll
    for (int j = 0; j < WTN; ++j)
      #pragma unroll
      for (int r = 0; r < 4; ++r) {
        int m = m0 + wm + i * 16 + quad * 4 + r;
        int n = n0 + wn + j * 16 + l16;
        float v = acc[i][j][r];
        if (BIAS) v += bias[n];
        if (ACT == 1) v = 1.0f / (1.0f + __expf(-v));
        if (OUT_BF16)
          ((__bf16*)Cz)[(size_t)m * N + n] = (__bf16)v;
        else
          ((float*)Cz)[(size_t)m * N + n] = v;
      }
}

// Router: split-K reduce + 2-layer router + top-2 -> DENSE gates (no atomics).
__global__ __launch_bounds__(256) void router_kernel(
    const float* __restrict__ contP, const float* __restrict__ s2c_b,
    const float* __restrict__ rW1, const float* __restrict__ rb1,
    const float* __restrict__ rW2, const float* __restrict__ rb2,
    __bf16* __restrict__ contB, float* __restrict__ gates) {
  const int wave = threadIdx.x >> 6, lane = threadIdx.x & 63;
  const int n = blockIdx.x * 4 + wave;
  const size_t base = (size_t)n * 64 + lane;
  const size_t slab = (size_t)TOK * 64;
  float c = contP[base] + contP[base + slab] + contP[base + 2 * slab] +
            contP[base + 3 * slab] + s2c_b[lane];
  contB[base] = (__bf16)c;
  float acc = rb1[lane];
  #pragma unroll
  for (int i = 0; i < 64; ++i) {
    float ci = __shfl(c, i);
    acc = fmaf(ci, rW1[i * 64 + lane], acc);
  }
  float t = tanhf(acc);
  float logit[8];
  #pragma unroll
  for (int e = 0; e < 8; ++e) {
    float v = t * rW2[lane * 8 + e];
    #pragma unroll
    for (int o = 32; o; o >>= 1) v += __shfl_xor(v, o);
    logit[e] = v + rb2[e];
  }
  float mx = logit[0];
  #pragma unroll
  for (int e = 1; e < 8; ++e) mx = fmaxf(mx, logit[e]);
  float p[8];
  #pragma unroll
  for (int e = 0; e < 8; ++e) p[e] = __expf(logit[e] - mx);
  float v0 = p[0]; int e0 = 0;
  #pragma unroll
  for (int e = 1; e < 8; ++e) if (p[e] > v0) { v0 = p[e]; e0 = e; }
  float v1 = -1.0f; int e1 = 0;
  #pragma unroll
  for (int e = 0; e < 8; ++e) if (e != e0 && p[e] > v1) { v1 = p[e]; e1 = e; }
  float inv = 1.0f / (v0 + v1);
  if (lane < 8) {
    float g = (lane == e0) ? v0 * inv : (lane == e1) ? v1 * inv : 0.0f;
    gates[(size_t)n * 8 + lane] = g;
  }
}

// Dense MoE: block = 128 consecutive tokens x expert e; swizzled LDS tiles.
__global__ __launch_bounds__(256) void moe_fused_kernel(
    const __bf16* __restrict__ contB, const __bf16* __restrict__ We1T,
    const __bf16* __restrict__ We2T, const float* __restrict__ be1,
    const float* __restrict__ be2, const float* __restrict__ gates,
    float* __restrict__ out_flat) {
  constexpr int TT = 128;
  const int e = blockIdx.y;
  const int t0 = blockIdx.x * TT;
  __shared__ __bf16 cont_s[TT * 64];
  __shared__ __bf16 w1_s[64 * 64];
  __shared__ __bf16 w2_s[64 * 64];
  __shared__ __bf16 h_s[TT * 64];
  __shared__ float g_s[TT];
  const int tid = threadIdx.x;
  const int wave = tid >> 6, lane = tid & 63;
  const int quad = lane >> 4, l16 = lane & 15;
  if (tid < TT) g_s[tid] = gates[(size_t)(t0 + tid) * 8 + e];
  for (int i = tid; i < TT * 8; i += 256) {
    int r = i >> 3, cc = i & 7;
    *(uint4*)(cont_s + r * 64 + ((cc ^ (r & 7)) * 8)) =
        *(const uint4*)(contB + (size_t)(t0 + r) * 64 + cc * 8);
  }
  const int wtok = wave * 32;
  f32x4 acc2[2][4] = {};
  for (int hc = 0; hc < HHALF; hc += 64) {
    __syncthreads();
    for (int c = tid; c < 512; c += 256) {
      int r = c >> 3, cc = c & 7;
      *(uint4*)(w1_s + r * 64 + ((cc ^ (r & 7)) * 8)) =
          *(const uint4*)(We1T + ((size_t)e * HHALF + hc + r) * 64 + cc * 8);
      *(uint4*)(w2_s + r * 64 + ((cc ^ (r & 7)) * 8)) =
          *(const uint4*)(We2T + ((size_t)e * 64 + r) * HHALF + hc + cc * 8);
    }
    __syncthreads();
    f32x4 acc1[2][4] = {};
    #pragma unroll
    for (int kk = 0; kk < 2; ++kk) {
      bf16x8 af[2], bfr[4];
      #pragma unroll
      for (int i = 0; i < 2; ++i) {
        int row = wtok + i * 16 + l16;
        af[i] = *(const bf16x8*)(cont_s + row * 64 + (((kk * 4 + quad) ^ (row & 7)) * 8));
      }
      #pragma unroll
      for (int j = 0; j < 4; ++j) {
        int row = j * 16 + l16;
        bfr[j] = *(const bf16x8*)(w1_s + row * 64 + (((kk * 4 + quad) ^ (row & 7)) * 8));
      }
      #pragma unroll
      for (int i = 0; i < 2; ++i)
        #pragma unroll
        for (int j = 0; j < 4; ++j)
          acc1[i][j] = __builtin_amdgcn_mfma_f32_16x16x32_bf16(af[i], bfr[j], acc1[i][j], 0, 0, 0);
    }
    #pragma unroll
    for (int i = 0; i < 2; ++i)
      #pragma unroll
      for (int j = 0; j < 4; ++j)
        #pragma unroll
        for (int r = 0; r < 4; ++r) {
          int tr = wtok + i * 16 + quad * 4 + r;
          int hcol = j * 16 + l16;
          float v = acc1[i][j][r] + be1[e * HHALF + hc + hcol];
          h_s[tr * 64 + (((hcol >> 3) ^ (tr & 7)) * 8) + (hcol & 7)] =
              (__bf16)fmaxf(v, 0.0f);
        }
    #pragma unroll
    for (int kk = 0; kk < 2; ++kk) {
      bf16x8 af[2], bfr[4];
      #pragma unroll
      for (int i = 0; i < 2; ++i) {
        int row = wtok + i * 16 + l16;
        af[i] = *(const bf16x8*)(h_s + row * 64 + (((kk * 4 + quad) ^ (row & 7)) * 8));
      }
      #pragma unroll
      for (int j = 0; j < 4; ++j) {
        int row = j * 16 + l16;
        bfr[j] = *(const bf16x8*)(w2_s + row * 64 + (((kk * 4 + quad) ^ (row & 7)) * 8));
      }
      #pragma unroll
      for (int i = 0; i < 2; ++i)
        #pragma unroll
        for (int j = 0; j < 4; ++j)
          acc2[i][j] = __builtin_amdgcn_mfma_f32_16x16x32_bf16(af[i], bfr[j], acc2[i][j], 0, 0, 0);
    }
  }
  #pragma unroll
  for (int i = 0; i < 2; ++i)
    #pragma unroll
    for (int j = 0; j < 4; ++j)
      #pragma unroll
      for (int r = 0; r < 4; ++r) {
        int tr = wtok + i * 16 + quad * 4 + r;
        int m = j * 16 + l16;
        float g = g_s[tr];
        if (g != 0.0f)
          atomicAdd(out_flat + (size_t)(t0 + tr) * 64 + m,
                    g * (acc2[i][j][r] + be2[e * 64 + m]));
      }
}

__global__ __launch_bounds__(256) void ln_kernel(
    const float* __restrict__ x, const float* __restrict__ g,
    const float* __restrict__ b, float* __restrict__ out) {
  const int row = blockIdx.x;
  const float4 v = ((const float4*)(x + (size_t)row * 1024))[threadIdx.x];
  float s1 = v.x + v.y + v.z + v.w;
  float s2 = v.x * v.x + v.y * v.y + v.z * v.z + v.w * v.w;
  #pragma unroll
  for (int o = 32; o; o >>= 1) { s1 += __shfl_xor(s1, o); s2 += __shfl_xor(s2, o); }
  __shared__ float ws1[4], ws2[4];
  const int wave = threadIdx.x >> 6, lane = threadIdx.x & 63;
  if (lane == 0) { ws1[wave] = s1; ws2[wave] = s2; }
  __syncthreads();
  s1 = ws1[0] + ws1[1] + ws1[2] + ws1[3];
  s2 = ws2[0] + ws2[1] + ws2[2] + ws2[3];
  const float mu = s1 * (1.0f / 1024.0f);
  const float var = s2 * (1.0f / 1024.0f) - mu * mu;
  const float inv = rsqrtf(var + 1e-5f);
  const int col = threadIdx.x * 4;
  const float4 gv = *(const float4*)(g + col);
  const float4 bv = *(const float4*)(b + col);
  float4 o;
  o.x = (v.x - mu) * inv * gv.x + bv.x;
  o.y = (v.y - mu) * inv * gv.y + bv.y;
  o.z = (v.z - mu) * inv * gv.z + bv.z;
  o.w = (v.w - mu) * inv * gv.w + bv.w;
  *(float4*)(out + (size_t)row * 1024 + col) = o;
}

extern "C" void kernel_launch(void* const* d_in, const int* in_sizes, int n_in,
                              void* d_out, int out_size, void* d_ws, size_t ws_size,
                              hipStream_t stream) {
  const float* X     = (const float*)d_in[0];
  const float* enc_W = (const float*)d_in[1];
  const float* enc_b = (const float*)d_in[2];
  const float* s2c_W = (const float*)d_in[3];
  const float* s2c_b = (const float*)d_in[4];
  const float* rW1   = (const float*)d_in[5];
  const float* rb1   = (const float*)d_in[6];
  const float* rW2   = (const float*)d_in[7];
  const float* rb2   = (const float*)d_in[8];
  const float* We1   = (const float*)d_in[9];
  const float* be1   = (const float*)d_in[10];
  const float* We2   = (const float*)d_in[11];
  const float* be2   = (const float*)d_in[12];
  const float* c2s_W = (const float*)d_in[13];
  const float* c2s_b = (const float*)d_in[14];
  const float* dec_W = (const float*)d_in[15];
  const float* dec_b = (const float*)d_in[16];
  const float* ln_g  = (const float*)d_in[17];
  const float* ln_b  = (const float*)d_in[18];
  float* out = (float*)d_out;

  // ---- workspace layout with explicit aliasing (~78 MB total) ----
  char* ws = (char*)d_ws;
  size_t off = 0;
  auto take = [&](size_t bytes) -> char* {
    char* p = ws + off;
    off = (off + bytes + 255) & ~(size_t)255;
    return p;
  };
  const size_t SLAB = (size_t)TOK * HDIM * 2;       // 33,554,432
  char*   slabA     = take(SLAB);
  char*   slabB     = take(SLAB);
  __bf16* encWT     = (__bf16*)take((size_t)HDIM * DMODEL * 2);
  __bf16* s2cWT     = (__bf16*)take((size_t)MDIM * HDIM * 2);
  __bf16* c2sWT     = (__bf16*)take((size_t)HDIM * MDIM * 2);
  __bf16* decWT     = (__bf16*)take((size_t)DMODEL * HDIM * 2);
  __bf16* We1T      = (__bf16*)take((size_t)NEXP * HHALF * MDIM * 2);
  __bf16* We2T      = (__bf16*)take((size_t)NEXP * MDIM * HHALF * 2);
  __bf16* contB     = (__bf16*)take((size_t)TOK * MDIM * 2);
  float*  gates     = (float*)take((size_t)TOK * NEXP * 4);
  float*  outFlat   = (float*)take((size_t)TOK * MDIM * 4);
  __bf16* outFlatB  = (__bf16*)take((size_t)TOK * MDIM * 2);
  if (off > ws_size) return;  // insufficient workspace -> clean correctness fail

  __bf16* Xb        = (__bf16*)slabA;                       // dead after GEMM1
  float*  contP     = (float*)(slabA + (size_t)TOK * DMODEL * 2);  // dead after router
  __bf16* spikesMoe = (__bf16*)slabA;                       // born at GEMM3
  __bf16* spikesEnc = (__bf16*)slabB;                       // dead after GEMM2
  float*  decoded   = (float*)slabB;                        // born at GEMM4

  hipMemsetAsync(outFlat, 0, (size_t)TOK * MDIM * 4, stream);

  // fused preamble: cvt(X) + 6 weight transposes in ONE launch
  preamble_kernel<<<PREAMBLE_BLOCKS, 256, 0, stream>>>(
      X, Xb, enc_W, encWT, s2c_W, s2cWT, c2s_W, c2sWT, dec_W, decWT,
      We1, We1T, We2, We2T);

  // GEMM1: spikesEnc = sigmoid(X @ enc_W + b)   8192x2048, K=1024
  gemm_bt<128, 128, 1, 1, 1><<<dim3(TOK / 128, HDIM / 128, 1), 256, 0, stream>>>(
      Xb, encWT, enc_b, spikesEnc, TOK, HDIM, DMODEL);
  // GEMM2 (split-K x4): contP[z] = spikesEnc @ s2c_W partials   8192x64, K=2048
  gemm_bt<128, 64, 0, 0, 0><<<dim3(TOK / 128, 1, 4), 256, 0, stream>>>(
      spikesEnc, s2cWT, nullptr, contP, TOK, MDIM, HDIM);
  // router: reduce partials + bias, top-2 -> dense gates (no atomics)
  router_kernel<<<TOK / 4, 256, 0, stream>>>(contP, s2c_b, rW1, rb1, rW2, rb2,
                                             contB, gates);
  // dense MoE -> outFlat (fp32; 2 effective atomic adds per element)
  moe_fused_kernel<<<dim3(TOK / 128, NEXP), 256, 0, stream>>>(
      contB, We1T, We2T, be1, be2, gates, outFlat);
  cvt_bf16_kernel<<<TOK * MDIM / 4 / 256, 256, 0, stream>>>(outFlat, outFlatB, TOK * MDIM / 4);
  // GEMM3: spikesMoe = sigmoid(outFlat @ c2s_W + b)   8192x2048, K=64
  gemm_bt<128, 128, 1, 1, 1><<<dim3(TOK / 128, HDIM / 128, 1), 256, 0, stream>>>(
      outFlatB, c2sWT, c2s_b, spikesMoe, TOK, HDIM, MDIM);
  // GEMM4: decoded = sigmoid(spikesMoe @ dec_W + b)   8192x1024, K=2048
  gemm_bt<128, 128, 0, 1, 1><<<dim3(TOK / 128, DMODEL / 128, 1), 256, 0, stream>>>(
      spikesMoe, decWT, dec_b, decoded, TOK, DMODEL, HDIM);
  ln_kernel<<<TOK, 256, 0, stream>>>(decoded, ln_g, ln_b, out);
}

// Round 9
// 316.109 us; speedup vs baseline: 1.1429x; 1.0309x over previous
//
#include <hip/hip_runtime.h>
#include <hip/hip_bf16.h>
#include <cstdint>
#include <cstddef>

#define TOK    8192
#define DMODEL 1024
#define HDIM   2048
#define MDIM   64
#define NEXP   8
#define HHALF  1024

using f32x4  = __attribute__((ext_vector_type(4))) float;
using bf16x8 = __attribute__((ext_vector_type(8))) __bf16;
using bf16x4 = __attribute__((ext_vector_type(4))) __bf16;

// async global->LDS, 16B per lane. LDS dest is wave-uniform base + lane*16.
__device__ __forceinline__ void async16(const void* g, void* l) {
  __builtin_amdgcn_global_load_lds(
      (const __attribute__((address_space(1))) unsigned int*)g,
      (__attribute__((address_space(3))) unsigned int*)l, 16, 0, 0);
}

// One-launch preamble: cvt(X) + transpose-cvt of all 6 weight tensors.
__global__ __launch_bounds__(256) void preamble_kernel(
    const float* __restrict__ X, __bf16* __restrict__ Xb,
    const float* __restrict__ encW, __bf16* __restrict__ encWT,
    const float* __restrict__ s2cW, __bf16* __restrict__ s2cWT,
    const float* __restrict__ c2sW, __bf16* __restrict__ c2sWT,
    const float* __restrict__ decW, __bf16* __restrict__ decWT,
    const float* __restrict__ We1, __bf16* __restrict__ We1T,
    const float* __restrict__ We2, __bf16* __restrict__ We2T) {
  __shared__ float ts[32][33];
  const int tid = threadIdx.x;
  int b = blockIdx.x;
  if (b < 8192) {  // X: 8192x1024 fp32 -> bf16 (float4 per thread)
    int i = b * 256 + tid;
    float4 v = ((const float4*)X)[i];
    bf16x4 o = { (__bf16)v.x, (__bf16)v.y, (__bf16)v.z, (__bf16)v.w };
    ((bf16x4*)Xb)[i] = o;
    return;
  }
  b -= 8192;
  const float* in; __bf16* outp; int R, C, tx, ty;
  if (b < 2048)              { in = encW; outp = encWT; R = 1024; C = 2048; tx = b % 64; ty = b / 64; }
  else if ((b -= 2048) < 128){ in = s2cW; outp = s2cWT; R = 2048; C = 64;   tx = b % 2;  ty = b / 2;  }
  else if ((b -= 128) < 128) { in = c2sW; outp = c2sWT; R = 64;   C = 2048; tx = b % 64; ty = b / 64; }
  else if ((b -= 128) < 2048){ in = decW; outp = decWT; R = 2048; C = 1024; tx = b % 32; ty = b / 32; }
  else if ((b -= 2048) < 512){ int s = b / 64, t = b % 64;
                               in = We1 + (size_t)s * 65536; outp = We1T + (size_t)s * 65536;
                               R = 64; C = 1024; tx = t % 32; ty = t / 32; }
  else                       { b -= 512; int s = b / 64, t = b % 64;
                               in = We2 + (size_t)s * 65536; outp = We2T + (size_t)s * 65536;
                               R = 1024; C = 64; tx = t % 2; ty = t / 2; }
  const int c0 = tx * 32, r0 = ty * 32;
  const int x = tid & 31, y = tid >> 5;
  #pragma unroll
  for (int i = y; i < 32; i += 8) ts[i][x] = in[(size_t)(r0 + i) * C + c0 + x];
  __syncthreads();
  #pragma unroll
  for (int i = y; i < 32; i += 8)
    outp[(size_t)(c0 + i) * R + r0 + x] = (__bf16)ts[x][i];
}
#define PREAMBLE_BLOCKS (8192 + 2048 + 128 + 128 + 2048 + 512 + 512)

// C = act(A @ Bt^T [+ bias]); A: MxK bf16 (row-major), Bt: NxK bf16.
// BK=64, global_load_lds staging, XOR-swizzled 16B chunks, hoisted pointers.
// SUMA: A-tile = bf16(A + A2) staged via register path (for K=64 one-shot).
// Split-K via gridDim.z: z-slice computes K/gridDim.z, writes slab at Cout + z*M*N.
template <int BM, int BN, int OUT_BF16, int ACT, int BIAS, int SUMA>
__global__ __launch_bounds__(256) void gemm_bt(
    const __bf16* __restrict__ A, const __bf16* __restrict__ Bt,
    const float* __restrict__ bias, void* __restrict__ Cout,
    int M, int N, int K, const __bf16* __restrict__ A2) {
  constexpr int BK = 64;               // 8 chunks of 16B per row
  constexpr int WTM = BM / 32;
  constexpr int WTN = BN / 32;
  __shared__ __bf16 As[BM * BK];
  __shared__ __bf16 Bs[BN * BK];
  const int tid = threadIdx.x;
  const int wave = tid >> 6, lane = tid & 63;
  const int quad = lane >> 4, l16 = lane & 15;
  const int m0 = blockIdx.x * BM, n0 = blockIdx.y * BN;
  const int ks = K / gridDim.z;
  const int kbeg = blockIdx.z * ks;
  const int wm = (wave & 1) * (BM / 2);
  const int wn = (wave >> 1) * (BN / 2);
  const int lrow = lane >> 3;
  const int lchunk = lane & 7;
  constexpr int A_ISSUES = BM / 32;
  constexpr int B_ISSUES = BN / 32;
  f32x4 acc[WTM][WTN] = {};

  const __bf16* aSrc[A_ISSUES];
  const __bf16* bSrc[B_ISSUES];
  #pragma unroll
  for (int t = 0; t < A_ISSUES; ++t) {
    int row = (t * 4 + wave) * 8 + lrow;
    aSrc[t] = A + (size_t)(m0 + row) * K + kbeg + (lchunk ^ (row & 7)) * 8;
  }
  #pragma unroll
  for (int t = 0; t < B_ISSUES; ++t) {
    int row = (t * 4 + wave) * 8 + lrow;
    bSrc[t] = Bt + (size_t)(n0 + row) * K + kbeg + (lchunk ^ (row & 7)) * 8;
  }
  int aOff[WTM][2], bOff[WTN][2];
  #pragma unroll
  for (int i = 0; i < WTM; ++i) {
    int row = wm + i * 16 + l16;
    #pragma unroll
    for (int kk = 0; kk < 2; ++kk)
      aOff[i][kk] = row * BK + (((kk * 4 + quad) ^ (row & 7)) * 8);
  }
  #pragma unroll
  for (int j = 0; j < WTN; ++j) {
    int row = wn + j * 16 + l16;
    #pragma unroll
    for (int kk = 0; kk < 2; ++kk)
      bOff[j][kk] = row * BK + (((kk * 4 + quad) ^ (row & 7)) * 8);
  }

  const int niter = ks / BK;
  for (int it = 0; it < niter; ++it) {
    __syncthreads();
    if (SUMA) {
      // register-path A staging: bf16(A + A2), swizzled dest (same layout as
      // async path: LDS slot s holds source chunk s^(row&7))
      #pragma unroll
      for (int t = 0; t < A_ISSUES; ++t) {
        int row = (t * 4 + wave) * 8 + lrow;
        size_t go = (size_t)(m0 + row) * K + kbeg + it * BK + lchunk * 8;
        bf16x8 a0 = *(const bf16x8*)(A + go);
        bf16x8 a1 = *(const bf16x8*)(A2 + go);
        bf16x8 s;
        #pragma unroll
        for (int q = 0; q < 8; ++q) s[q] = (__bf16)((float)a0[q] + (float)a1[q]);
        *(bf16x8*)(As + row * BK + ((lchunk ^ (row & 7)) * 8)) = s;
      }
    } else {
      #pragma unroll
      for (int t = 0; t < A_ISSUES; ++t) {
        async16(aSrc[t], As + (t * 4 + wave) * 8 * BK);
        aSrc[t] += BK;
      }
    }
    #pragma unroll
    for (int t = 0; t < B_ISSUES; ++t) {
      async16(bSrc[t], Bs + (t * 4 + wave) * 8 * BK);
      bSrc[t] += BK;
    }
    __syncthreads();
    #pragma unroll
    for (int kk = 0; kk < 2; ++kk) {
      bf16x8 af[WTM], bfr[WTN];
      #pragma unroll
      for (int i = 0; i < WTM; ++i) af[i] = *(const bf16x8*)(As + aOff[i][kk]);
      #pragma unroll
      for (int j = 0; j < WTN; ++j) bfr[j] = *(const bf16x8*)(Bs + bOff[j][kk]);
      #pragma unroll
      for (int i = 0; i < WTM; ++i)
        #pragma unroll
        for (int j = 0; j < WTN; ++j)
          acc[i][j] = __builtin_amdgcn_mfma_f32_16x16x32_bf16(af[i], bfr[j], acc[i][j], 0, 0, 0);
    }
  }

  char* Cz = (char*)Cout + (size_t)blockIdx.z * M * N * (OUT_BF16 ? 2 : 4);
  #pragma unroll
  for (int i = 0; i < WTM; ++i)
    #pragma unroll
    for (int j = 0; j < WTN; ++j)
      #pragma unroll
      for (int r = 0; r < 4; ++r) {
        int m = m0 + wm + i * 16 + quad * 4 + r;
        int n = n0 + wn + j * 16 + l16;
        float v = acc[i][j][r];
        if (BIAS) v += bias[n];
        if (ACT == 1) v = 1.0f / (1.0f + __expf(-v));
        if (OUT_BF16)
          ((__bf16*)Cz)[(size_t)m * N + n] = (__bf16)v;
        else
          ((float*)Cz)[(size_t)m * N + n] = v;
      }
}

// Router: split-K reduce + 2-layer router + top-2 -> packed e01 + g01.
__global__ __launch_bounds__(256) void router_kernel(
    const float* __restrict__ contP, const float* __restrict__ s2c_b,
    const float* __restrict__ rW1, const float* __restrict__ rb1,
    const float* __restrict__ rW2, const float* __restrict__ rb2,
    __bf16* __restrict__ contB, int* __restrict__ e01,
    float2* __restrict__ g01) {
  const int wave = threadIdx.x >> 6, lane = threadIdx.x & 63;
  const int n = blockIdx.x * 4 + wave;
  const size_t base = (size_t)n * 64 + lane;
  const size_t slab = (size_t)TOK * 64;
  float c = contP[base] + contP[base + slab] + contP[base + 2 * slab] +
            contP[base + 3 * slab] + s2c_b[lane];
  contB[base] = (__bf16)c;
  float acc = rb1[lane];
  #pragma unroll
  for (int i = 0; i < 64; ++i) {
    float ci = __shfl(c, i);
    acc = fmaf(ci, rW1[i * 64 + lane], acc);
  }
  float t = tanhf(acc);
  float logit[8];
  #pragma unroll
  for (int e = 0; e < 8; ++e) {
    float v = t * rW2[lane * 8 + e];
    #pragma unroll
    for (int o = 32; o; o >>= 1) v += __shfl_xor(v, o);
    logit[e] = v + rb2[e];
  }
  float mx = logit[0];
  #pragma unroll
  for (int e = 1; e < 8; ++e) mx = fmaxf(mx, logit[e]);
  float p[8];
  #pragma unroll
  for (int e = 0; e < 8; ++e) p[e] = __expf(logit[e] - mx);
  float v0 = p[0]; int e0 = 0;
  #pragma unroll
  for (int e = 1; e < 8; ++e) if (p[e] > v0) { v0 = p[e]; e0 = e; }
  float v1 = -1.0f; int e1 = 0;
  #pragma unroll
  for (int e = 0; e < 8; ++e) if (e != e0 && p[e] > v1) { v1 = p[e]; e1 = e; }
  float inv = 1.0f / (v0 + v1);
  if (lane == 0) {
    e01[n] = e0 | (e1 << 8);
    g01[n] = make_float2(v0 * inv, v1 * inv);
  }
}

// Dense MoE: block = 128 consecutive tokens x expert e; swizzled LDS tiles.
// Output: plain bf16 stores into rank-slabs (slab0 from each token's top-1
// expert block, slab1 from top-2). Exactly-once per token per slab; no atomics.
__global__ __launch_bounds__(256) void moe_fused_kernel(
    const __bf16* __restrict__ contB, const __bf16* __restrict__ We1T,
    const __bf16* __restrict__ We2T, const float* __restrict__ be1,
    const float* __restrict__ be2, const int* __restrict__ e01,
    const float2* __restrict__ g01, __bf16* __restrict__ slab0,
    __bf16* __restrict__ slab1) {
  constexpr int TT = 128;
  const int e = blockIdx.y;
  const int t0 = blockIdx.x * TT;
  __shared__ __bf16 cont_s[TT * 64];
  __shared__ __bf16 w1_s[64 * 64];
  __shared__ __bf16 w2_s[64 * 64];
  __shared__ __bf16 h_s[TT * 64];
  __shared__ int   e01_s[TT];
  __shared__ float g0_s[TT], g1_s[TT];
  const int tid = threadIdx.x;
  const int wave = tid >> 6, lane = tid & 63;
  const int quad = lane >> 4, l16 = lane & 15;
  if (tid < TT) {
    e01_s[tid] = e01[t0 + tid];
    float2 g = g01[t0 + tid];
    g0_s[tid] = g.x; g1_s[tid] = g.y;
  }
  for (int i = tid; i < TT * 8; i += 256) {
    int r = i >> 3, cc = i & 7;
    *(uint4*)(cont_s + r * 64 + ((cc ^ (r & 7)) * 8)) =
        *(const uint4*)(contB + (size_t)(t0 + r) * 64 + cc * 8);
  }
  const int wtok = wave * 32;
  f32x4 acc2[2][4] = {};
  for (int hc = 0; hc < HHALF; hc += 64) {
    __syncthreads();
    for (int c = tid; c < 512; c += 256) {
      int r = c >> 3, cc = c & 7;
      *(uint4*)(w1_s + r * 64 + ((cc ^ (r & 7)) * 8)) =
          *(const uint4*)(We1T + ((size_t)e * HHALF + hc + r) * 64 + cc * 8);
      *(uint4*)(w2_s + r * 64 + ((cc ^ (r & 7)) * 8)) =
          *(const uint4*)(We2T + ((size_t)e * 64 + r) * HHALF + hc + cc * 8);
    }
    __syncthreads();
    f32x4 acc1[2][4] = {};
    #pragma unroll
    for (int kk = 0; kk < 2; ++kk) {
      bf16x8 af[2], bfr[4];
      #pragma unroll
      for (int i = 0; i < 2; ++i) {
        int row = wtok + i * 16 + l16;
        af[i] = *(const bf16x8*)(cont_s + row * 64 + (((kk * 4 + quad) ^ (row & 7)) * 8));
      }
      #pragma unroll
      for (int j = 0; j < 4; ++j) {
        int row = j * 16 + l16;
        bfr[j] = *(const bf16x8*)(w1_s + row * 64 + (((kk * 4 + quad) ^ (row & 7)) * 8));
      }
      #pragma unroll
      for (int i = 0; i < 2; ++i)
        #pragma unroll
        for (int j = 0; j < 4; ++j)
          acc1[i][j] = __builtin_amdgcn_mfma_f32_16x16x32_bf16(af[i], bfr[j], acc1[i][j], 0, 0, 0);
    }
    #pragma unroll
    for (int i = 0; i < 2; ++i)
      #pragma unroll
      for (int j = 0; j < 4; ++j)
        #pragma unroll
        for (int r = 0; r < 4; ++r) {
          int tr = wtok + i * 16 + quad * 4 + r;
          int hcol = j * 16 + l16;
          float v = acc1[i][j][r] + be1[e * HHALF + hc + hcol];
          h_s[tr * 64 + (((hcol >> 3) ^ (tr & 7)) * 8) + (hcol & 7)] =
              (__bf16)fmaxf(v, 0.0f);
        }
    #pragma unroll
    for (int kk = 0; kk < 2; ++kk) {
      bf16x8 af[2], bfr[4];
      #pragma unroll
      for (int i = 0; i < 2; ++i) {
        int row = wtok + i * 16 + l16;
        af[i] = *(const bf16x8*)(h_s + row * 64 + (((kk * 4 + quad) ^ (row & 7)) * 8));
      }
      #pragma unroll
      for (int j = 0; j < 4; ++j) {
        int row = j * 16 + l16;
        bfr[j] = *(const bf16x8*)(w2_s + row * 64 + (((kk * 4 + quad) ^ (row & 7)) * 8));
      }
      #pragma unroll
      for (int i = 0; i < 2; ++i)
        #pragma unroll
        for (int j = 0; j < 4; ++j)
          acc2[i][j] = __builtin_amdgcn_mfma_f32_16x16x32_bf16(af[i], bfr[j], acc2[i][j], 0, 0, 0);
    }
  }
  #pragma unroll
  for (int i = 0; i < 2; ++i)
    #pragma unroll
    for (int j = 0; j < 4; ++j)
      #pragma unroll
      for (int r = 0; r < 4; ++r) {
        int tr = wtok + i * 16 + quad * 4 + r;
        int m = j * 16 + l16;
        int pe = e01_s[tr];
        size_t o = (size_t)(t0 + tr) * 64 + m;
        if ((pe & 0xff) == e)
          slab0[o] = (__bf16)(g0_s[tr] * (acc2[i][j][r] + be2[e * 64 + m]));
        else if (((pe >> 8) & 0xff) == e)
          slab1[o] = (__bf16)(g1_s[tr] * (acc2[i][j][r] + be2[e * 64 + m]));
      }
}

__global__ __launch_bounds__(256) void ln_kernel(
    const float* __restrict__ x, const float* __restrict__ g,
    const float* __restrict__ b, float* __restrict__ out) {
  const int row = blockIdx.x;
  const float4 v = ((const float4*)(x + (size_t)row * 1024))[threadIdx.x];
  float s1 = v.x + v.y + v.z + v.w;
  float s2 = v.x * v.x + v.y * v.y + v.z * v.z + v.w * v.w;
  #pragma unroll
  for (int o = 32; o; o >>= 1) { s1 += __shfl_xor(s1, o); s2 += __shfl_xor(s2, o); }
  __shared__ float ws1[4], ws2[4];
  const int wave = threadIdx.x >> 6, lane = threadIdx.x & 63;
  if (lane == 0) { ws1[wave] = s1; ws2[wave] = s2; }
  __syncthreads();
  s1 = ws1[0] + ws1[1] + ws1[2] + ws1[3];
  s2 = ws2[0] + ws2[1] + ws2[2] + ws2[3];
  const float mu = s1 * (1.0f / 1024.0f);
  const float var = s2 * (1.0f / 1024.0f) - mu * mu;
  const float inv = rsqrtf(var + 1e-5f);
  const int col = threadIdx.x * 4;
  const float4 gv = *(const float4*)(g + col);
  const float4 bv = *(const float4*)(b + col);
  float4 o;
  o.x = (v.x - mu) * inv * gv.x + bv.x;
  o.y = (v.y - mu) * inv * gv.y + bv.y;
  o.z = (v.z - mu) * inv * gv.z + bv.z;
  o.w = (v.w - mu) * inv * gv.w + bv.w;
  *(float4*)(out + (size_t)row * 1024 + col) = o;
}

extern "C" void kernel_launch(void* const* d_in, const int* in_sizes, int n_in,
                              void* d_out, int out_size, void* d_ws, size_t ws_size,
                              hipStream_t stream) {
  const float* X     = (const float*)d_in[0];
  const float* enc_W = (const float*)d_in[1];
  const float* enc_b = (const float*)d_in[2];
  const float* s2c_W = (const float*)d_in[3];
  const float* s2c_b = (const float*)d_in[4];
  const float* rW1   = (const float*)d_in[5];
  const float* rb1   = (const float*)d_in[6];
  const float* rW2   = (const float*)d_in[7];
  const float* rb2   = (const float*)d_in[8];
  const float* We1   = (const float*)d_in[9];
  const float* be1   = (const float*)d_in[10];
  const float* We2   = (const float*)d_in[11];
  const float* be2   = (const float*)d_in[12];
  const float* c2s_W = (const float*)d_in[13];
  const float* c2s_b = (const float*)d_in[14];
  const float* dec_W = (const float*)d_in[15];
  const float* dec_b = (const float*)d_in[16];
  const float* ln_g  = (const float*)d_in[17];
  const float* ln_b  = (const float*)d_in[18];
  float* out = (float*)d_out;

  // ---- workspace layout with explicit aliasing (~78 MB total) ----
  char* ws = (char*)d_ws;
  size_t off = 0;
  auto take = [&](size_t bytes) -> char* {
    char* p = ws + off;
    off = (off + bytes + 255) & ~(size_t)255;
    return p;
  };
  const size_t SLAB = (size_t)TOK * HDIM * 2;       // 33,554,432
  char*   slabA     = take(SLAB);
  char*   slabB     = take(SLAB);
  __bf16* encWT     = (__bf16*)take((size_t)HDIM * DMODEL * 2);
  __bf16* s2cWT     = (__bf16*)take((size_t)MDIM * HDIM * 2);
  __bf16* c2sWT     = (__bf16*)take((size_t)HDIM * MDIM * 2);
  __bf16* decWT     = (__bf16*)take((size_t)DMODEL * HDIM * 2);
  __bf16* We1T      = (__bf16*)take((size_t)NEXP * HHALF * MDIM * 2);
  __bf16* We2T      = (__bf16*)take((size_t)NEXP * MDIM * HHALF * 2);
  __bf16* contB     = (__bf16*)take((size_t)TOK * MDIM * 2);
  int*    e01       = (int*)take((size_t)TOK * 4);
  float2* g01       = (float2*)take((size_t)TOK * 8);
  __bf16* oslab0    = (__bf16*)take((size_t)TOK * MDIM * 2);
  __bf16* oslab1    = (__bf16*)take((size_t)TOK * MDIM * 2);
  if (off > ws_size) return;  // insufficient workspace -> clean correctness fail

  __bf16* Xb        = (__bf16*)slabA;                       // dead after GEMM1
  float*  contP     = (float*)(slabA + (size_t)TOK * DMODEL * 2);  // dead after router
  __bf16* spikesMoe = (__bf16*)slabA;                       // born at GEMM3
  __bf16* spikesEnc = (__bf16*)slabB;                       // dead after GEMM2
  float*  decoded   = (float*)slabB;                        // born at GEMM4

  // fused preamble: cvt(X) + 6 weight transposes in ONE launch
  preamble_kernel<<<PREAMBLE_BLOCKS, 256, 0, stream>>>(
      X, Xb, enc_W, encWT, s2c_W, s2cWT, c2s_W, c2sWT, dec_W, decWT,
      We1, We1T, We2, We2T);

  // GEMM1: spikesEnc = sigmoid(X @ enc_W + b)   8192x2048, K=1024
  gemm_bt<128, 128, 1, 1, 1, 0><<<dim3(TOK / 128, HDIM / 128, 1), 256, 0, stream>>>(
      Xb, encWT, enc_b, spikesEnc, TOK, HDIM, DMODEL, nullptr);
  // GEMM2 (split-K x4): contP[z] = spikesEnc @ s2c_W partials   8192x64, K=2048
  gemm_bt<128, 64, 0, 0, 0, 0><<<dim3(TOK / 128, 1, 4), 256, 0, stream>>>(
      spikesEnc, s2cWT, nullptr, contP, TOK, MDIM, HDIM, nullptr);
  // router: reduce partials + bias, top-2 -> e01/g01 (no atomics)
  router_kernel<<<TOK / 4, 256, 0, stream>>>(contP, s2c_b, rW1, rb1, rW2, rb2,
                                             contB, e01, g01);
  // dense MoE -> rank-slabs (bf16 plain stores; no memset, no atomics)
  moe_fused_kernel<<<dim3(TOK / 128, NEXP), 256, 0, stream>>>(
      contB, We1T, We2T, be1, be2, e01, g01, oslab0, oslab1);
  // GEMM3 (SUMA): spikesMoe = sigmoid((slab0+slab1) @ c2s_W + b)  8192x2048, K=64
  gemm_bt<128, 128, 1, 1, 1, 1><<<dim3(TOK / 128, HDIM / 128, 1), 256, 0, stream>>>(
      oslab0, c2sWT, c2s_b, spikesMoe, TOK, HDIM, MDIM, oslab1);
  // GEMM4: decoded = sigmoid(spikesMoe @ dec_W + b)   8192x1024, K=2048
  gemm_bt<128, 128, 0, 1, 1, 0><<<dim3(TOK / 128, DMODEL / 128, 1), 256, 0, stream>>>(
      spikesMoe, decWT, dec_b, decoded, TOK, DMODEL, HDIM, nullptr);
  ln_kernel<<<TOK, 256, 0, stream>>>(decoded, ln_g, ln_b, out);
}